// Round 3
// baseline (564.233 us; speedup 1.0000x reference)
//
#include <hip/hip_runtime.h>
#include <math.h>

#define D 128
#define B2D 256
#define NSEG 64
#define MAXC 512
#define PSTRIDE 144   // floats per chunk-partial: [0]=m, [1]=s, [8..135]=acc[128]

// ---------------- init / copy ----------------
__global__ void k_zero(float* p, int n) {
    int i = blockIdx.x * blockDim.x + threadIdx.x;
    if (i < n) p[i] = 0.f;
}

__global__ void k_copy(const float* __restrict__ s, float* __restrict__ d, int n) {
    int i = blockIdx.x * blockDim.x + threadIdx.x;
    if (i < n) d[i] = s[i];
}

// ---------------- segment offsets (edge_batch is sorted) ----------------
__global__ void k_ofs(const int* __restrict__ eb, int* __restrict__ seg_ofs, int E) {
    int e = blockIdx.x * blockDim.x + threadIdx.x;
    if (e >= E) return;
    int b = eb[e];
    if (e == 0) {
        for (int j = 0; j <= b; ++j) seg_ofs[j] = 0;
    } else {
        int p = eb[e - 1];
        if (p != b) for (int j = p + 1; j <= b; ++j) seg_ofs[j] = e;
    }
    if (e == E - 1) {
        for (int j = b + 1; j <= NSEG; ++j) seg_ofs[j] = E;
    }
}

// ---------------- per-segment chunking: chunk counts, prefix, edges-per-wave ----------------
__global__ void k_seginfo(const int* __restrict__ seg_ofs, int* __restrict__ pre,
                          int* __restrict__ epw) {
    __shared__ int cnt[NSEG];
    int b = threadIdx.x;
    if (b < NSEG) {
        int len = seg_ofs[b + 1] - seg_ofs[b];
        int e = 62;
        int c = (len + e - 1) / e;
        if (c > MAXC) { e = (len + MAXC - 1) / MAXC; c = (len + e - 1) / e; }
        if (len == 0) c = 0;
        epw[b] = e;
        cnt[b] = c;
    }
    __syncthreads();
    if (threadIdx.x == 0) {
        int acc = 0;
        for (int j = 0; j < NSEG; ++j) { pre[j] = acc; acc += cnt[j]; }
        pre[NSEG] = acc;
    }
}

// ---------------- LSTM cell: one block per batch row ----------------
__global__ __launch_bounds__(512) void k_lstm(
        const float* __restrict__ w_ih, const float* __restrict__ w_hh,
        const float* __restrict__ b_ih, const float* __restrict__ b_hh,
        float* __restrict__ h, float* __restrict__ c, float* __restrict__ q_star) {
    int b = blockIdx.x;   // 0..63
    int t = threadIdx.x;  // 0..511  (gate index, order i|f|g|o)
    __shared__ float s_x[B2D];
    __shared__ float s_h[D];
    __shared__ float s_g[4 * D];
    if (t < B2D) s_x[t] = q_star[b * B2D + t];
    else if (t < B2D + D) s_h[t - B2D] = h[b * D + (t - B2D)];
    __syncthreads();

    float acc = b_ih[t] + b_hh[t];
    const float* wr = w_ih + (size_t)t * B2D;
    #pragma unroll 8
    for (int k = 0; k < B2D; k += 4) {
        float4 w4 = *(const float4*)(wr + k);
        acc += w4.x * s_x[k] + w4.y * s_x[k + 1] + w4.z * s_x[k + 2] + w4.w * s_x[k + 3];
    }
    const float* wh = w_hh + (size_t)t * D;
    #pragma unroll 8
    for (int k = 0; k < D; k += 4) {
        float4 w4 = *(const float4*)(wh + k);
        acc += w4.x * s_h[k] + w4.y * s_h[k + 1] + w4.z * s_h[k + 2] + w4.w * s_h[k + 3];
    }
    s_g[t] = acc;
    __syncthreads();

    if (t < D) {
        float gi = s_g[t], gf = s_g[t + D], gg = s_g[t + 2 * D], go = s_g[t + 3 * D];
        float si = 1.f / (1.f + expf(-gi));
        float sf = 1.f / (1.f + expf(-gf));
        float so = 1.f / (1.f + expf(-go));
        float cn = sf * c[b * D + t] + si * tanhf(gg);
        float hn = so * tanhf(cn);
        c[b * D + t] = cn;
        h[b * D + t] = hn;
        q_star[b * B2D + t] = hn;            // q half
    }
}

__device__ __forceinline__ float red32(float p) {
    p += __shfl_xor(p, 16, 32);
    p += __shfl_xor(p, 8, 32);
    p += __shfl_xor(p, 4, 32);
    p += __shfl_xor(p, 2, 32);
    p += __shfl_xor(p, 1, 32);
    return p;
}

// ---------------- fused single-pass: logits + online softmax + weighted accumulate ----------------
// One wave per chunk; chunks never cross segment boundaries. Each half-wave
// (32 lanes x float4 = one 512B feat row) handles 4 edges per iteration to
// keep 4 loads in flight and amortize the online-softmax update.
__global__ __launch_bounds__(256) void k_pass(
        const float* __restrict__ feat, const int* __restrict__ seg_ofs,
        const int* __restrict__ pre, const int* __restrict__ epw,
        const float* __restrict__ h, float* __restrict__ part) {
    __shared__ int s_pre[NSEG + 1], s_ofs[NSEG + 1], s_epw[NSEG];
    int tid = threadIdx.x;
    if (tid <= NSEG) { s_pre[tid] = pre[tid]; s_ofs[tid] = seg_ofs[tid]; }
    if (tid < NSEG) s_epw[tid] = epw[tid];
    __syncthreads();
    int total = s_pre[NSEG];
    int wave = (blockIdx.x * blockDim.x + tid) >> 6;
    int nwaves = (gridDim.x * blockDim.x) >> 6;
    int lane = tid & 63, half = lane >> 5, sl = lane & 31;

    for (int cid = wave; cid < total; cid += nwaves) {
        // binary search: largest b with s_pre[b] <= cid
        int lo = 0, hi = NSEG - 1;
        while (lo < hi) {
            int mid = (lo + hi + 1) >> 1;
            if (s_pre[mid] <= cid) lo = mid; else hi = mid - 1;
        }
        int b = lo;
        int chunk = cid - s_pre[b];
        int e = s_epw[b];
        long s0 = (long)s_ofs[b] + (long)chunk * e;
        long s1 = (long)s_ofs[b + 1];
        long send = s0 + e;
        if (send < s1) s1 = send;

        float4 q4 = *(const float4*)(h + (size_t)b * D + sl * 4);
        float m = -INFINITY, ssum = 0.f;
        float4 acc = make_float4(0.f, 0.f, 0.f, 0.f);

        long ee = s0;
        // main loop: 8 edges per wave iteration (4 per half-wave)
        for (; ee + 8 <= s1; ee += 8) {
            const float* base = feat + (size_t)(ee + half) * D + sl * 4;
            float4 f0 = *(const float4*)(base);
            float4 f1 = *(const float4*)(base + 2 * D);
            float4 f2 = *(const float4*)(base + 4 * D);
            float4 f3 = *(const float4*)(base + 6 * D);
            float p0 = f0.x * q4.x + f0.y * q4.y + f0.z * q4.z + f0.w * q4.w;
            float p1 = f1.x * q4.x + f1.y * q4.y + f1.z * q4.z + f1.w * q4.w;
            float p2 = f2.x * q4.x + f2.y * q4.y + f2.z * q4.z + f2.w * q4.w;
            float p3 = f3.x * q4.x + f3.y * q4.y + f3.z * q4.z + f3.w * q4.w;
            p0 = red32(p0); p1 = red32(p1); p2 = red32(p2); p3 = red32(p3);
            float mx = fmaxf(fmaxf(p0, p1), fmaxf(p2, p3));
            if (mx > m) {
                float sc = __expf(m - mx);   // exp(-inf)=0 handles first batch
                ssum *= sc;
                acc.x *= sc; acc.y *= sc; acc.z *= sc; acc.w *= sc;
                m = mx;
            }
            float w0 = __expf(p0 - m), w1 = __expf(p1 - m);
            float w2 = __expf(p2 - m), w3 = __expf(p3 - m);
            ssum += w0 + w1 + w2 + w3;
            acc.x += w0 * f0.x + w1 * f1.x + w2 * f2.x + w3 * f3.x;
            acc.y += w0 * f0.y + w1 * f1.y + w2 * f2.y + w3 * f3.y;
            acc.z += w0 * f0.z + w1 * f1.z + w2 * f2.z + w3 * f3.z;
            acc.w += w0 * f0.w + w1 * f1.w + w2 * f2.w + w3 * f3.w;
        }
        // tail: 2 edges per iteration, guarded
        for (; ee < s1; ee += 2) {
            long my_e = ee + half;
            bool valid = my_e < s1;
            float4 f4 = make_float4(0.f, 0.f, 0.f, 0.f);
            if (valid) f4 = *(const float4*)(feat + (size_t)my_e * D + sl * 4);
            float p = f4.x * q4.x + f4.y * q4.y + f4.z * q4.z + f4.w * q4.w;
            p = red32(p);
            if (valid) {
                float nm = fmaxf(m, p);
                float sc = __expf(m - nm);
                float we = __expf(p - nm);
                ssum = ssum * sc + we;
                acc.x = acc.x * sc + we * f4.x;
                acc.y = acc.y * sc + we * f4.y;
                acc.z = acc.z * sc + we * f4.z;
                acc.w = acc.w * sc + we * f4.w;
                m = nm;
            }
        }
        // merge the two half-wave states
        float m_o = __shfl_xor(m, 32);
        float s_o = __shfl_xor(ssum, 32);
        float4 a_o;
        a_o.x = __shfl_xor(acc.x, 32);
        a_o.y = __shfl_xor(acc.y, 32);
        a_o.z = __shfl_xor(acc.z, 32);
        a_o.w = __shfl_xor(acc.w, 32);
        float nm = fmaxf(m, m_o);            // at least one half saw an edge
        float sa = __expf(m - nm), sb = __expf(m_o - nm);
        float sm = ssum * sa + s_o * sb;
        float4 am;
        am.x = acc.x * sa + a_o.x * sb;
        am.y = acc.y * sa + a_o.y * sb;
        am.z = acc.z * sa + a_o.z * sb;
        am.w = acc.w * sa + a_o.w * sb;

        float* dst = part + (size_t)cid * PSTRIDE;
        if (lane == 0) { dst[0] = nm; dst[1] = sm; }
        if (half == 0) *(float4*)(dst + 8 + sl * 4) = am;
    }
}

// ---------------- combine chunk partials per segment (no atomics) ----------------
__global__ __launch_bounds__(128) void k_combine(
        const float* __restrict__ part, const int* __restrict__ pre,
        float* __restrict__ q_star) {
    int b = blockIdx.x, t = threadIdx.x;
    int c0 = pre[b], c1 = pre[b + 1];
    int nc = c1 - c0;
    __shared__ float s_w[MAXC];
    __shared__ float red[128];

    // pass 1: global max of chunk maxima
    float M = -INFINITY;
    for (int c = t; c < nc; c += 128) M = fmaxf(M, part[(size_t)(c0 + c) * PSTRIDE]);
    red[t] = M; __syncthreads();
    for (int o = 64; o > 0; o >>= 1) {
        if (t < o) red[t] = fmaxf(red[t], red[t + o]);
        __syncthreads();
    }
    M = red[0]; __syncthreads();

    // pass 2: per-chunk weights + rescaled sum
    float S = 0.f;
    for (int c = t; c < nc; c += 128) {
        const float* pe = part + (size_t)(c0 + c) * PSTRIDE;
        float w = __expf(pe[0] - M);
        s_w[c] = w;
        S += w * pe[1];
    }
    red[t] = S; __syncthreads();
    for (int o = 64; o > 0; o >>= 1) {
        if (t < o) red[t] += red[t + o];
        __syncthreads();
    }
    S = red[0]; __syncthreads();

    // pass 3: rescaled accumulator, one feature dim per thread
    float R = 0.f;
    for (int c = 0; c < nc; ++c)
        R += s_w[c] * part[(size_t)(c0 + c) * PSTRIDE + 8 + t];
    q_star[b * B2D + D + t] = R / (S + 1e-8f);
}

extern "C" void kernel_launch(void* const* d_in, const int* in_sizes, int n_in,
                              void* d_out, int out_size, void* d_ws, size_t ws_size,
                              hipStream_t stream) {
    const float* feat = (const float*)d_in[0];
    const int*   eb   = (const int*)d_in[1];
    const float* w_ih = (const float*)d_in[2];
    const float* w_hh = (const float*)d_in[3];
    const float* b_ih = (const float*)d_in[4];
    const float* b_hh = (const float*)d_in[5];
    float* out = (float*)d_out;
    float* ws  = (float*)d_ws;
    const int E = in_sizes[1];   // 500000

    // workspace layout (float offsets)
    float* h      = ws;                  // 64*128
    float* c      = ws + 8192;           // 64*128
    float* q_star = ws + 16384;          // 64*256
    int*   seg    = (int*)(ws + 32768);  // 65
    int*   pre    = (int*)(ws + 32840);  // 65
    int*   epw    = (int*)(ws + 32912);  // 64
    float* part   = ws + 33024;          // up to 64*512*144 floats (~19 MB)

    // zero LSTM state + q_star
    k_zero<<<128, 256, 0, stream>>>(ws, 32768);
    // segment offsets (input is sorted) + chunk mapping
    k_ofs<<<(E + 255) / 256, 256, 0, stream>>>(eb, seg, E);
    k_seginfo<<<1, 64, 0, stream>>>(seg, pre, epw);

    const int BLOCKS = 2048, THREADS = 256;  // 8192 waves, full device residency
    for (int it = 0; it < 3; ++it) {
        k_lstm<<<NSEG, 512, 0, stream>>>(w_ih, w_hh, b_ih, b_hh, h, c, q_star);
        k_pass<<<BLOCKS, THREADS, 0, stream>>>(feat, seg, pre, epw, h, part);
        k_combine<<<NSEG, 128, 0, stream>>>(part, pre, q_star);
    }
    k_copy<<<64, 256, 0, stream>>>(q_star, out, out_size);
}